// Round 6
// baseline (46.037 us; speedup 1.0000x reference)
//
#include <hip/hip_runtime.h>
#include <hip/hip_bf16.h>

constexpr int B = 1024, S = 128, E = 256, C = 256, T = 12;

typedef short s8v __attribute__((ext_vector_type(8)));   // 8 x bf16 bits
typedef float f4v __attribute__((ext_vector_type(4)));

__device__ __forceinline__ short f2bf(float f) {
    unsigned u = __builtin_bit_cast(unsigned, f);
    return (short)((u + 0x7FFFu + ((u >> 16) & 1u)) >> 16);
}
__device__ __forceinline__ s8v cvt8(float4 a, float4 b) {
    s8v o;
    o[0] = f2bf(a.x); o[1] = f2bf(a.y); o[2] = f2bf(a.z); o[3] = f2bf(a.w);
    o[4] = f2bf(b.x); o[5] = f2bf(b.y); o[6] = f2bf(b.z); o[7] = f2bf(b.w);
    return o;
}

// ---------------- Kernel 1: pred[t] = c_last @ Wk_w[t]^T (bias cancels in log-softmax) ----
// 128x128 tiles, 512 threads, reads c/wkw f32 directly (cvt in staging). Also zeroes out[0].
__global__ __launch_bounds__(512) void pred_kernel(
    const float* __restrict__ c, const float* __restrict__ wkw,
    const int* __restrict__ tsp, short* __restrict__ pred, float* __restrict__ out)
{
    // bijective XCD swizzle: 192 blocks = 8 xcd * 24; (t,eb) pairs clustered per xcd
    int wgid = blockIdx.x;
    int xcd = wgid & 7, q = wgid >> 3;          // q in 0..23
    int pr = xcd * 3 + (q >> 3);                // 0..23 : (t,eb) pair id
    int bb = q & 7;                              // b-row block (128 rows)
    int t = pr >> 1, eb = pr & 1;                // e-col block (128 cols)
    if (wgid == 0 && threadIdx.x == 0) out[0] = 0.0f;
    const int ts = tsp[0];

    __shared__ __align__(16) short AS[128 * 256];   // c_last tile (bf16), 64 KB
    __shared__ __align__(16) short BS[128 * 256];   // wkw tile (bf16), 64 KB
    const int tid = threadIdx.x;

    #pragma unroll
    for (int it = 0; it < 8; ++it) {
        int idx = it * 512 + tid;
        int r = idx >> 5, s = idx & 31;
        const float4* pa = reinterpret_cast<const float4*>(
            c + (size_t)(bb * 128 + r) * S * C + (size_t)ts * C + s * 8);
        *reinterpret_cast<s8v*>(AS + r * 256 + ((s ^ (r & 7)) * 8)) = cvt8(pa[0], pa[1]);
        const float4* pb = reinterpret_cast<const float4*>(
            wkw + ((size_t)t * E + eb * 128 + r) * 256 + s * 8);
        *reinterpret_cast<s8v*>(BS + r * 256 + ((s ^ (r & 7)) * 8)) = cvt8(pb[0], pb[1]);
    }
    __syncthreads();

    const int wv = tid >> 6, ln = tid & 63;
    const int wr = wv >> 2, wc = wv & 3;        // 2 row-groups(64) x 4 col-groups(32)
    const int lr = ln & 15, lg = ln >> 4;
    f4v acc[4][2] = {};

    #pragma unroll
    for (int kk = 0; kk < 8; ++kk) {
        int slot = kk * 4 + lg;
        s8v a[4], b[2];
        #pragma unroll
        for (int m = 0; m < 4; ++m) {
            int r = wr * 64 + m * 16 + lr;
            a[m] = *reinterpret_cast<const s8v*>(AS + r * 256 + ((slot ^ (r & 7)) * 8));
        }
        #pragma unroll
        for (int n = 0; n < 2; ++n) {
            int r = wc * 32 + n * 16 + lr;
            b[n] = *reinterpret_cast<const s8v*>(BS + r * 256 + ((slot ^ (r & 7)) * 8));
        }
        #pragma unroll
        for (int m = 0; m < 4; ++m)
            #pragma unroll
            for (int n = 0; n < 2; ++n)
                acc[m][n] = __builtin_amdgcn_mfma_f32_16x16x32_bf16(a[m], b[n], acc[m][n], 0, 0, 0);
    }

    #pragma unroll
    for (int m = 0; m < 4; ++m)
        #pragma unroll
        for (int n = 0; n < 2; ++n)
            #pragma unroll
            for (int i = 0; i < 4; ++i) {
                int bg = bb * 128 + wr * 64 + m * 16 + lg * 4 + i;   // b row
                int eg = eb * 128 + wc * 32 + n * 16 + lr;           // e col
                pred[(size_t)t * B * E + (size_t)bg * E + eg] = f2bf(acc[m][n][i]);
            }
}

// ---------------- Kernel 2: full-row scores, pred direct from L2 (no staging, no barriers) --
// block = (rb: 32 enc rows, t). 256 thr = 4 waves, each wave owns 128 cols per pass,
// 2 passes of 512 cols. enc in LDS (one barrier); pred B-fragments loaded straight from
// global (L2-resident, 512 KB/t, XCD-clustered). Online logsumexp across passes; diag in
// registers; cross-wave merge + atomicAdd at the end.
__global__ __launch_bounds__(256) void score_kernel(
    const float* __restrict__ z, const short* __restrict__ pred,
    const int* __restrict__ tsp, float* __restrict__ out)
{
    // bijective XCD swizzle: 384 = 8 xcd * 48; same-t blocks clustered per XCD
    int bid = blockIdx.x;
    int g = (bid & 7) * 48 + (bid >> 3);   // 0..383
    int t = g >> 5;                        // 0..11
    int rb = g & 31;                       // 0..31
    const int ts = tsp[0];

    __shared__ __align__(16) short encS[32 * 256];   // 16 KB
    __shared__ float pm[4][32];
    __shared__ float ps[4][32];
    __shared__ float diagS[32];

    const int tid = threadIdx.x;
    const short* pred_t = pred + (size_t)t * B * E;

    // stage enc: 32 rows x 256, f32 -> bf16, XOR-swizzled
    #pragma unroll
    for (int it = 0; it < 4; ++it) {
        int idx = it * 256 + tid;
        int r = idx >> 5, s = idx & 31;
        const float4* pz = reinterpret_cast<const float4*>(
            z + (size_t)(rb * 32 + r) * S * E + (size_t)(ts + 1 + t) * E + s * 8);
        *reinterpret_cast<s8v*>(encS + r * 256 + ((s ^ (r & 7)) * 8)) = cvt8(pz[0], pz[1]);
    }
    __syncthreads();

    const int wv = tid >> 6, ln = tid & 63;
    const int lr = ln & 15, lg = ln >> 4;

    float m_run[2] = {-1e30f, -1e30f};
    float s_run[2] = {0.0f, 0.0f};
    float dreg[2] = {0.0f, 0.0f};
    int downer[2] = {0, 0};

    #pragma unroll
    for (int ci = 0; ci < 2; ++ci) {
        f4v acc[8][2] = {};
        // lane's pred column base for this pass: col = ci*512 + wv*128 + a*16 + lr
        const short* pbase = pred_t + (size_t)(ci * 512 + wv * 128 + lr) * 256 + lg * 8;

        #pragma unroll
        for (int ke = 0; ke < 8; ++ke) {
            s8v p[8], e[2];
            #pragma unroll
            for (int a = 0; a < 8; ++a)
                p[a] = *reinterpret_cast<const s8v*>(pbase + a * 4096 + ke * 32);
            #pragma unroll
            for (int b = 0; b < 2; ++b) {
                int er = b * 16 + lr;
                int sf = ke * 4 + lg;
                e[b] = *reinterpret_cast<const s8v*>(encS + er * 256 + ((sf ^ (er & 7)) * 8));
            }
            #pragma unroll
            for (int a = 0; a < 8; ++a)
                #pragma unroll
                for (int b = 0; b < 2; ++b)
                    acc[a][b] = __builtin_amdgcn_mfma_f32_16x16x32_bf16(p[a], e[b], acc[a][b], 0, 0, 0);
        }

        // online logsumexp update per row-tile; diag capture
        #pragma unroll
        for (int b = 0; b < 2; ++b) {
            float mx = -1e30f;
            #pragma unroll
            for (int a = 0; a < 8; ++a)
                #pragma unroll
                for (int i = 0; i < 4; ++i) mx = fmaxf(mx, acc[a][b][i]);
            mx = fmaxf(mx, __shfl_xor(mx, 16));
            mx = fmaxf(mx, __shfl_xor(mx, 32));
            float sm = 0.0f;
            #pragma unroll
            for (int a = 0; a < 8; ++a)
                #pragma unroll
                for (int i = 0; i < 4; ++i) sm += __expf(acc[a][b][i] - mx);
            sm += __shfl_xor(sm, 16);
            sm += __shfl_xor(sm, 32);

            int rg = rb * 32 + b * 16 + lr;
            if ((rg >> 9) == ci) {
                int dl = rg & 511;    // col within pass: wv(2) | a(3) | lg(2) | i(2)
                if ((dl >> 7) == wv && ((dl >> 2) & 3) == lg) {
                    #pragma unroll
                    for (int a = 0; a < 8; ++a)
                        #pragma unroll
                        for (int i = 0; i < 4; ++i)
                            if (((dl >> 4) & 7) == a && (dl & 3) == i) dreg[b] = acc[a][b][i];
                    downer[b] = 1;
                }
            }
            float mn = fmaxf(m_run[b], mx);
            s_run[b] = s_run[b] * __expf(m_run[b] - mn) + sm * __expf(mx - mn);
            m_run[b] = mn;
        }
    }

    // cross-wave merge (4 waves cover same 32 rows, different cols)
    if (lg == 0) {
        pm[wv][lr]      = m_run[0];  ps[wv][lr]      = s_run[0];
        pm[wv][16 + lr] = m_run[1];  ps[wv][16 + lr] = s_run[1];
    }
    if (downer[0]) diagS[lr]      = dreg[0];
    if (downer[1]) diagS[16 + lr] = dreg[1];
    __syncthreads();

    if (tid < 32) {
        float M = pm[0][tid];
        #pragma unroll
        for (int w = 1; w < 4; ++w) M = fmaxf(M, pm[w][tid]);
        float Ss = 0.0f;
        #pragma unroll
        for (int w = 0; w < 4; ++w) Ss += ps[w][tid] * __expf(pm[w][tid] - M);
        float val = diagS[tid] - (M + logf(Ss));
        #pragma unroll
        for (int o = 1; o < 32; o <<= 1) val += __shfl_xor(val, o);
        if (tid == 0) atomicAdd(out, -val / (float)(B * T));
    }
}

extern "C" void kernel_launch(void* const* d_in, const int* in_sizes, int n_in,
                              void* d_out, int out_size, void* d_ws, size_t ws_size,
                              hipStream_t stream)
{
    (void)in_sizes; (void)n_in; (void)out_size; (void)ws_size;
    const float* z   = (const float*)d_in[0];
    const float* c   = (const float*)d_in[1];
    const float* wkw = (const float*)d_in[2];
    const int*   tsp = (const int*)d_in[4];

    short* pred = (short*)d_ws;                  // T*B*E bf16 = 6,291,456 B

    pred_kernel<<<192, 512, 0, stream>>>(c, wkw, tsp, pred, (float*)d_out);
    score_kernel<<<384, 256, 0, stream>>>(z, pred, tsp, (float*)d_out);
}

// Round 7
// 28.825 us; speedup vs baseline: 1.5971x; 1.5971x over previous
//
#include <hip/hip_runtime.h>
#include <hip/hip_bf16.h>

constexpr int B = 1024, S = 128, E = 256, C = 256, T = 12;

typedef short s8v __attribute__((ext_vector_type(8)));   // 8 x bf16 bits
typedef float f4v __attribute__((ext_vector_type(4)));

__device__ __forceinline__ short f2bf(float f) {
    unsigned u = __builtin_bit_cast(unsigned, f);
    return (short)((u + 0x7FFFu + ((u >> 16) & 1u)) >> 16);
}
__device__ __forceinline__ s8v cvt8(float4 a, float4 b) {
    s8v o;
    o[0] = f2bf(a.x); o[1] = f2bf(a.y); o[2] = f2bf(a.z); o[3] = f2bf(a.w);
    o[4] = f2bf(b.x); o[5] = f2bf(b.y); o[6] = f2bf(b.z); o[7] = f2bf(b.w);
    return o;
}

// ---------------- Kernel 1: pred[t] = c_last @ Wk_w[t]^T (bias cancels in log-softmax) ----
// 128x128 tiles, 512 threads, f32 in (cvt in staging). Also zero-inits rowsum and out.
__global__ __launch_bounds__(512) void pred_kernel(
    const float* __restrict__ c, const float* __restrict__ wkw,
    const int* __restrict__ tsp, short* __restrict__ pred,
    float* __restrict__ rowsum, float* __restrict__ out)
{
    // zero rowsum (12288 floats) + out
    {
        int gi = blockIdx.x * 512 + threadIdx.x;
        if (gi < T * B) rowsum[gi] = 0.0f;
        if (gi == 0) out[0] = 0.0f;
    }
    // bijective XCD swizzle: 192 blocks = 8 xcd * 24; (t,eb) pairs clustered per xcd
    int wgid = blockIdx.x;
    int xcd = wgid & 7, q = wgid >> 3;          // q in 0..23
    int pr = xcd * 3 + (q >> 3);                // 0..23 : (t,eb) pair id
    int bb = q & 7;                              // b-row block (128 rows)
    int t = pr >> 1, eb = pr & 1;                // e-col block (128 cols)
    const int ts = tsp[0];

    __shared__ __align__(16) short AS[128 * 256];   // c_last tile (bf16), 64 KB
    __shared__ __align__(16) short BS[128 * 256];   // wkw tile (bf16), 64 KB
    const int tid = threadIdx.x;

    #pragma unroll
    for (int it = 0; it < 8; ++it) {
        int idx = it * 512 + tid;
        int r = idx >> 5, s = idx & 31;
        const float4* pa = reinterpret_cast<const float4*>(
            c + (size_t)(bb * 128 + r) * S * C + (size_t)ts * C + s * 8);
        *reinterpret_cast<s8v*>(AS + r * 256 + ((s ^ (r & 7)) * 8)) = cvt8(pa[0], pa[1]);
        const float4* pb = reinterpret_cast<const float4*>(
            wkw + ((size_t)t * E + eb * 128 + r) * 256 + s * 8);
        *reinterpret_cast<s8v*>(BS + r * 256 + ((s ^ (r & 7)) * 8)) = cvt8(pb[0], pb[1]);
    }
    __syncthreads();

    const int wv = tid >> 6, ln = tid & 63;
    const int wr = wv >> 2, wc = wv & 3;        // 2 row-groups(64) x 4 col-groups(32)
    const int lr = ln & 15, lg = ln >> 4;
    f4v acc[4][2] = {};

    #pragma unroll
    for (int kk = 0; kk < 8; ++kk) {
        int slot = kk * 4 + lg;
        s8v a[4], b[2];
        #pragma unroll
        for (int m = 0; m < 4; ++m) {
            int r = wr * 64 + m * 16 + lr;
            a[m] = *reinterpret_cast<const s8v*>(AS + r * 256 + ((slot ^ (r & 7)) * 8));
        }
        #pragma unroll
        for (int n = 0; n < 2; ++n) {
            int r = wc * 32 + n * 16 + lr;
            b[n] = *reinterpret_cast<const s8v*>(BS + r * 256 + ((slot ^ (r & 7)) * 8));
        }
        #pragma unroll
        for (int m = 0; m < 4; ++m)
            #pragma unroll
            for (int n = 0; n < 2; ++n)
                acc[m][n] = __builtin_amdgcn_mfma_f32_16x16x32_bf16(a[m], b[n], acc[m][n], 0, 0, 0);
    }

    #pragma unroll
    for (int m = 0; m < 4; ++m)
        #pragma unroll
        for (int n = 0; n < 2; ++n)
            #pragma unroll
            for (int i = 0; i < 4; ++i) {
                int bg = bb * 128 + wr * 64 + m * 16 + lg * 4 + i;   // b row
                int eg = eb * 128 + wc * 32 + n * 16 + lr;           // e col
                pred[(size_t)t * B * E + (size_t)bg * E + eg] = f2bf(acc[m][n][i]);
            }
}

// ---------------- Kernel 2: scores tile + exp-sum partials (no-max) + diag ----------------
// R4's measured-best structure: 64 rows x 256 cols per block, 512 threads, pred staged in
// K-eighths (dbuf + 2-deep reg prefetch, 1 barrier/eighth). enc staged straight from f32 z.
// Epilogue: plain sum of exp(score) per row -> atomicAdd rowsum (f32-safe: |score| <~ 75).
__global__ __launch_bounds__(512) void score_kernel(
    const float* __restrict__ z, const short* __restrict__ pred,
    const int* __restrict__ tsp,
    float* __restrict__ rowsum, float* __restrict__ diag_g)
{
    // bijective swizzle: 768 = 8 xcd * 96; (ci,t) clustered per xcd (pred chunk L2-local)
    int wgid = blockIdx.x;
    int xcd = wgid & 7, q = wgid >> 3;           // q in 0..95
    int pairid = xcd * 6 + (q >> 4);             // 0..47
    int rb = q & 15;                              // enc row-block (64 rows)
    int t = pairid >> 2, ci = pairid & 3;         // col chunk (256 cols)
    const int ts = tsp[0];

    __shared__ __align__(16) char SM[65536];
    short* encS = reinterpret_cast<short*>(SM);              // 64x256 bf16 = 32 KB
    short* buf0 = reinterpret_cast<short*>(SM + 32768);      // pred eighth [4][256][8] = 16 KB
    short* buf1 = reinterpret_cast<short*>(SM + 49152);      // 16 KB

    const int tid = threadIdx.x;
    const short* pred_t = pred + (size_t)t * B * E;

    // per-thread pred chunk addresses: 2 chunks of 16B per eighth
    const int h0 = tid, h1 = tid + 512;
    const int col0 = h0 >> 2, sl0 = h0 & 3;
    const int col1 = h1 >> 2, sl1 = h1 & 3;
    const short* g0 = pred_t + (size_t)(ci * 256 + col0) * 256 + sl0 * 8;
    const short* g1 = pred_t + (size_t)(ci * 256 + col1) * 256 + sl1 * 8;
    const int l0 = sl0 * 2048 + col0 * 8;   // LDS element offsets
    const int l1 = sl1 * 2048 + col1 * 8;

    // prologue: issue eighth-0 loads, stage enc (f32->bf16), write eighth-0, issue eighth-1
    s8v R0 = *reinterpret_cast<const s8v*>(g0);
    s8v R1 = *reinterpret_cast<const s8v*>(g1);
    #pragma unroll
    for (int it = 0; it < 4; ++it) {
        int idx = it * 512 + tid;
        int r = idx >> 5, s = idx & 31;
        const float4* pz = reinterpret_cast<const float4*>(
            z + (size_t)(rb * 64 + r) * S * E + (size_t)(ts + 1 + t) * E + s * 8);
        *reinterpret_cast<s8v*>(encS + r * 256 + ((s ^ (r & 7)) * 8)) = cvt8(pz[0], pz[1]);
    }
    *reinterpret_cast<s8v*>(buf0 + l0) = R0;
    *reinterpret_cast<s8v*>(buf0 + l1) = R1;
    R0 = *reinterpret_cast<const s8v*>(g0 + 32);
    R1 = *reinterpret_cast<const s8v*>(g1 + 32);
    __syncthreads();

    const int wv = tid >> 6, ln = tid & 63;
    const int wr = wv >> 2, wc = wv & 3;          // 2 row-groups(32) x 4 col-groups(64)
    const int lr = ln & 15, lg = ln >> 4;
    f4v acc[4][2] = {};   // [a: col-tile][b: row-tile]

    #pragma unroll
    for (int ke = 0; ke < 8; ++ke) {
        short* cur = (ke & 1) ? buf1 : buf0;
        short* nxt = (ke & 1) ? buf0 : buf1;
        if (ke < 7) {   // write prefetched eighth ke+1
            *reinterpret_cast<s8v*>(nxt + l0) = R0;
            *reinterpret_cast<s8v*>(nxt + l1) = R1;
        }
        if (ke < 6) {   // issue loads for eighth ke+2
            R0 = *reinterpret_cast<const s8v*>(g0 + (ke + 2) * 32);
            R1 = *reinterpret_cast<const s8v*>(g1 + (ke + 2) * 32);
        }
        // MFMA on eighth ke
        s8v p[4], e[2];
        #pragma unroll
        for (int a = 0; a < 4; ++a)
            p[a] = *reinterpret_cast<const s8v*>(cur + lg * 2048 + (wc * 64 + a * 16 + lr) * 8);
        #pragma unroll
        for (int b = 0; b < 2; ++b) {
            int er = wr * 32 + b * 16 + lr;
            int sf = ke * 4 + lg;
            e[b] = *reinterpret_cast<const s8v*>(encS + er * 256 + ((sf ^ (er & 7)) * 8));
        }
        #pragma unroll
        for (int a = 0; a < 4; ++a)
            #pragma unroll
            for (int b = 0; b < 2; ++b)
                acc[a][b] = __builtin_amdgcn_mfma_f32_16x16x32_bf16(p[a], e[b], acc[a][b], 0, 0, 0);
        __syncthreads();
    }

    // acc[a][b][i] = score(row = wr*32+b*16+lr, col = ci*256 + wc*64 + a*16 + lg*4 + i)
    #pragma unroll
    for (int b = 0; b < 2; ++b) {
        float sm = 0.0f;
        #pragma unroll
        for (int a = 0; a < 4; ++a)
            #pragma unroll
            for (int i = 0; i < 4; ++i) sm += __expf(acc[a][b][i]);
        sm += __shfl_xor(sm, 16);
        sm += __shfl_xor(sm, 32);
        int rg = rb * 64 + wr * 32 + b * 16 + lr;
        if (lg == 0) atomicAdd(&rowsum[t * B + rg], sm);

        // diagonal element (exactly one lane in one block owns it)
        if ((rg >> 8) == ci) {
            int dl = rg & 255;
            if ((dl >> 6) == wc && ((dl >> 2) & 3) == lg) {
                float dv = 0.0f;
                #pragma unroll
                for (int a = 0; a < 4; ++a)
                    #pragma unroll
                    for (int i = 0; i < 4; ++i)
                        if (((dl >> 4) & 3) == a && (dl & 3) == i) dv = acc[a][b][i];
                diag_g[t * B + rg] = dv;
            }
        }
    }
}

// ---------------- Kernel 3: val = diag - log(rowsum); sum -> out ----------------
__global__ __launch_bounds__(1024) void final_kernel(
    const float* __restrict__ rowsum, const float* __restrict__ diag_g,
    float* __restrict__ out)
{
    int row = blockIdx.x * 1024 + threadIdx.x;   // 0..12287
    float val = diag_g[row] - logf(rowsum[row]);
    #pragma unroll
    for (int o = 1; o < 64; o <<= 1) val += __shfl_xor(val, o);
    __shared__ float red[16];
    int wv = threadIdx.x >> 6, lnn = threadIdx.x & 63;
    if (lnn == 0) red[wv] = val;
    __syncthreads();
    if (threadIdx.x == 0) {
        float tot = 0.0f;
        #pragma unroll
        for (int w = 0; w < 16; ++w) tot += red[w];
        atomicAdd(out, -tot / (float)(B * T));
    }
}

extern "C" void kernel_launch(void* const* d_in, const int* in_sizes, int n_in,
                              void* d_out, int out_size, void* d_ws, size_t ws_size,
                              hipStream_t stream)
{
    (void)in_sizes; (void)n_in; (void)out_size; (void)ws_size;
    const float* z   = (const float*)d_in[0];
    const float* c   = (const float*)d_in[1];
    const float* wkw = (const float*)d_in[2];
    const int*   tsp = (const int*)d_in[4];

    char* w = (char*)d_ws;
    short* pred   = (short*)(w);                 // T*B*E bf16 = 6,291,456 B
    float* rowsum = (float*)(w + 6291456);       // T*B f32 = 49,152 B
    float* diag_g = (float*)(w + 6340608);       // T*B f32 = 49,152 B

    pred_kernel<<<192, 512, 0, stream>>>(c, wkw, tsp, pred, rowsum, (float*)d_out);
    score_kernel<<<768, 512, 0, stream>>>(z, pred, tsp, rowsum, diag_g);
    final_kernel<<<12, 1024, 0, stream>>>(rowsum, diag_g, (float*)d_out);
}